// Round 2
// baseline (244.055 us; speedup 1.0000x reference)
//
#include <hip/hip_runtime.h>
#include <stdint.h>

#define QD 512   // query_dim
#define KD 256   // key_dim
#define NBATCH 2048
#define NK 512   // n_keys

// ---------------------------------------------------------------------------
// Kernel 1: TQ[b][k] = sum_q Q[b][q] * W[k][q] + bias[k]      (B=2048, KD=256)
// 512 blocks x 256 threads; each block handles 4 batch rows staged in LDS;
// thread t owns output column t and streams W[t][:] (L2-resident, 512 KB).
// Also zero-inits the mask-dtype flag (block 0) — stream order makes it safe.
// ---------------------------------------------------------------------------
__global__ __launch_bounds__(256) void tq_gemm(const float* __restrict__ Q,
                                               const float* __restrict__ W,
                                               const float* __restrict__ bias,
                                               float* __restrict__ TQ,
                                               int* __restrict__ flag) {
    if (blockIdx.x == 0 && threadIdx.x == 0) *flag = 0;

    __shared__ float qs[4][QD];
    const int b0 = blockIdx.x * 4;

    // cooperative load: 4*512 floats = 512 float4s by 256 threads
    const float4* Qv = (const float4*)(Q + (size_t)b0 * QD);
    float4* qsv = (float4*)&qs[0][0];
    qsv[threadIdx.x]       = Qv[threadIdx.x];
    qsv[threadIdx.x + 256] = Qv[threadIdx.x + 256];
    __syncthreads();

    const int k = threadIdx.x;                       // output column 0..255
    const float4* Wv = (const float4*)(W + (size_t)k * QD);

    float a0 = 0.f, a1 = 0.f, a2 = 0.f, a3 = 0.f;
#pragma unroll 4
    for (int kk = 0; kk < QD / 4; ++kk) {
        float4 w4 = Wv[kk];
        float4 q0 = *(const float4*)&qs[0][kk * 4];  // broadcast reads (free)
        float4 q1 = *(const float4*)&qs[1][kk * 4];
        float4 q2 = *(const float4*)&qs[2][kk * 4];
        float4 q3 = *(const float4*)&qs[3][kk * 4];
        a0 += w4.x * q0.x + w4.y * q0.y + w4.z * q0.z + w4.w * q0.w;
        a1 += w4.x * q1.x + w4.y * q1.y + w4.z * q1.z + w4.w * q1.w;
        a2 += w4.x * q2.x + w4.y * q2.y + w4.z * q2.z + w4.w * q2.w;
        a3 += w4.x * q3.x + w4.y * q3.y + w4.z * q3.z + w4.w * q3.w;
    }
    const float bb = bias[k];
    TQ[(size_t)(b0 + 0) * KD + k] = a0 + bb;
    TQ[(size_t)(b0 + 1) * KD + k] = a1 + bb;
    TQ[(size_t)(b0 + 2) * KD + k] = a2 + bb;
    TQ[(size_t)(b0 + 3) * KD + k] = a3 + bb;
}

// ---------------------------------------------------------------------------
// Mask-dtype probe: OR-reduce the first nwords 32-bit words of the mask
// buffer. int32 bools -> every word in {0,1}. 1-byte bools -> upper bytes
// carry 0x01 in ~random words -> some word > 1 -> flag = 1.
// ---------------------------------------------------------------------------
__global__ __launch_bounds__(256) void detect_mask_dtype(const uint32_t* __restrict__ m,
                                                         int nwords,
                                                         int* __restrict__ flag) {
    uint32_t v = 0;
    for (int i = blockIdx.x * blockDim.x + threadIdx.x; i < nwords;
         i += gridDim.x * blockDim.x)
        v |= m[i];
#pragma unroll
    for (int off = 32; off > 0; off >>= 1)
        v |= (uint32_t)__shfl_xor((int)v, off, 64);
    if ((threadIdx.x & 63) == 0 && v > 1u) atomicOr(flag, 1);
}

// ---------------------------------------------------------------------------
// Kernel 2: fused  alpha = keys . tq  -> mask -> online softmax -> PV
// One block (256 thr = 4 waves) per batch. Each wave owns 128 key rows.
// One key row = 256 f32 = 64 lanes x float4 -> one coalesced 1 KB load.
// keys is read EXACTLY ONCE from HBM (1 GiB total).
// ---------------------------------------------------------------------------
__global__ __launch_bounds__(256) void attn_fused(const float* __restrict__ keys,
                                                  const void* __restrict__ maskp,
                                                  const float* __restrict__ TQ,
                                                  const int* __restrict__ flag,
                                                  float* __restrict__ out_att,
                                                  float* __restrict__ out_alpha) {
    const int b    = blockIdx.x;
    const int wave = threadIdx.x >> 6;
    const int lane = threadIdx.x & 63;

    __shared__ float s_alpha[NK];        // raw (masked) logits
    __shared__ float s_acc[4][KD];       // per-wave PV partials
    __shared__ float s_m[4], s_l[4];

    const int bytemask = *flag;          // wave-uniform, L2 broadcast

    const float4 tq4 = *(const float4*)(TQ + (size_t)b * KD + lane * 4);
    const float* kb  = keys + (size_t)b * NK * KD;
    const uint8_t* mb8  = (const uint8_t*)maskp + (size_t)b * NK;
    const int32_t* mb32 = (const int32_t*)maskp + (size_t)b * NK;

    float m = -1e30f, l = 0.f;
    float ax = 0.f, ay = 0.f, az = 0.f, aw = 0.f;

    const int n0 = wave * (NK / 4);      // this wave's 128 rows

    for (int i = 0; i < NK / 4; i += 4) {
        float4 k4[4];
#pragma unroll
        for (int r = 0; r < 4; ++r)
            k4[r] = *(const float4*)(kb + (size_t)(n0 + i + r) * KD + lane * 4);

#pragma unroll
        for (int r = 0; r < 4; ++r) {
            const int n = n0 + i + r;
            float part = k4[r].x * tq4.x + k4[r].y * tq4.y +
                         k4[r].z * tq4.z + k4[r].w * tq4.w;
#pragma unroll
            for (int off = 32; off > 0; off >>= 1)
                part += __shfl_xor(part, off, 64);

            const int masked = bytemask ? (mb8[n] != 0) : (mb32[n] != 0);
            const float aval = masked ? -INFINITY : part;
            if (lane == 0) s_alpha[n] = aval;

            // branch-free online softmax update (m starts at -1e30, never NaN)
            const float mn = fmaxf(m, aval);
            const float sc = __expf(m - mn);
            const float w  = __expf(aval - mn);
            l = l * sc + w;
            ax = ax * sc + w * k4[r].x;
            ay = ay * sc + w * k4[r].y;
            az = az * sc + w * k4[r].z;
            aw = aw * sc + w * k4[r].w;
            m = mn;
        }
    }

    if (lane == 0) { s_m[wave] = m; s_l[wave] = l; }
    *(float4*)&s_acc[wave][lane * 4] = make_float4(ax, ay, az, aw);
    __syncthreads();

    // cross-wave merge (all threads redundantly compute the scalars; cheap)
    const float M = fmaxf(fmaxf(s_m[0], s_m[1]), fmaxf(s_m[2], s_m[3]));
    const float sc0 = __expf(s_m[0] - M), sc1 = __expf(s_m[1] - M);
    const float sc2 = __expf(s_m[2] - M), sc3 = __expf(s_m[3] - M);
    const float L = s_l[0] * sc0 + s_l[1] * sc1 + s_l[2] * sc2 + s_l[3] * sc3;
    const float invL = 1.0f / L;

    const int t = threadIdx.x;
    const float o = (s_acc[0][t] * sc0 + s_acc[1][t] * sc1 +
                     s_acc[2][t] * sc2 + s_acc[3][t] * sc3) * invL;
    out_att[(size_t)b * KD + t] = o;

    // alpha_sm: exp(-inf - M) == 0 handles masked entries exactly
    out_alpha[(size_t)b * NK + t]       = __expf(s_alpha[t]       - M) * invL;
    out_alpha[(size_t)b * NK + t + 256] = __expf(s_alpha[t + 256] - M) * invL;
}

extern "C" void kernel_launch(void* const* d_in, const int* in_sizes, int n_in,
                              void* d_out, int out_size, void* d_ws, size_t ws_size,
                              hipStream_t stream) {
    const float* queries = (const float*)d_in[0];   // (2048, 512)
    const float* keys    = (const float*)d_in[1];   // (2048, 512, 256)
    // d_in[2] = trans_keys — unused by the reference
    const void*  mask    = d_in[3];                 // (2048, 512) bool (dtype probed)
    const float* W       = (const float*)d_in[4];   // (256, 512)
    const float* bias    = (const float*)d_in[5];   // (256,)

    float* out_att   = (float*)d_out;                         // (2048, 256)
    float* out_alpha = (float*)d_out + (size_t)NBATCH * KD;   // (2048, 512)
    float* TQ        = (float*)d_ws;                          // (2048, 256) scratch
    int*   flag      = (int*)((char*)d_ws + (size_t)NBATCH * KD * sizeof(float));

    const int mask_words = in_sizes[3] / 4;  // safe lower bound for both dtypes

    tq_gemm<<<NBATCH / 4, 256, 0, stream>>>(queries, W, bias, TQ, flag);
    detect_mask_dtype<<<256, 256, 0, stream>>>((const uint32_t*)mask, mask_words, flag);
    attn_fused<<<NBATCH, 256, 0, stream>>>(keys, mask, TQ, flag, out_att, out_alpha);
}